// Round 2
// baseline (392.668 us; speedup 1.0000x reference)
//
#include <hip/hip_runtime.h>
#include <cstdint>

#define BN_EPS 1e-5f

typedef unsigned int uint;

// ---------------------------------------------------------------------------
// x:  (32, 256, 28, 28) f32
// w1: (1024, 256, 3, 3)  conv1: 256 -> 1024 (groups collapse: same input)
// w2: (1024, 256, 3, 3)  conv2: grouped x4
// out: (32, 256, 28, 28) f32
// Packing: 256 ch -> 8 u32 words; bit (c%32) of word (c/32) = (v>=0)
// ---------------------------------------------------------------------------

__global__ __launch_bounds__(256) void kPrep(
    const float* __restrict__ s1, const float* __restrict__ b1,
    const float* __restrict__ m1, const float* __restrict__ v1,
    const float* __restrict__ s2, const float* __restrict__ b2,
    const float* __restrict__ m2, const float* __restrict__ v2,
    const float* __restrict__ lam,
    float* __restrict__ bnA1, float* __restrict__ bnB1,
    float* __restrict__ bnA2, float* __restrict__ bnB2) {
  int t = blockIdx.x * 256 + threadIdx.x;
  if (t >= 1024) return;
  float inv1 = s1[t] / sqrtf(v1[t] + BN_EPS);
  bnA1[t] = inv1;
  bnB1[t] = b1[t] - m1[t] * inv1;
  float inv2 = s2[t] / sqrtf(v2[t] + BN_EPS);
  float l = lam[t >> 8];
  bnA2[t] = inv2 * l;
  bnB2[t] = (b2[t] - m2[t] * inv2) * l;
}

__global__ __launch_bounds__(256) void kPackX(const float* __restrict__ x,
                                              uint* __restrict__ A1p) {
  int wg = blockIdx.x * 4 + (threadIdx.x >> 6);
  int lane = threadIdx.x & 63;
  int pixel = wg >> 2;
  int cb = wg & 3;
  int b = pixel / 784;
  int rem = pixel - b * 784;
  float v = x[(b * 256 + cb * 64 + lane) * 784 + rem];
  unsigned long long m = __ballot(v >= 0.0f);
  if (lane == 0) {
    A1p[pixel * 8 + cb * 2]     = (uint)m;
    A1p[pixel * 8 + cb * 2 + 1] = (uint)(m >> 32);
  }
}

__global__ __launch_bounds__(256) void kPackW(const float* __restrict__ w,
                                              uint* __restrict__ Wp) {
  int wg = blockIdx.x * 4 + (threadIdx.x >> 6);
  int lane = threadIdx.x & 63;
  int oc = wg / 36;
  int r = wg - oc * 36;
  int tap = r >> 2;
  int cb = r & 3;
  float v = w[(oc * 256 + cb * 64 + lane) * 9 + tap];
  unsigned long long m = __ballot(v >= 0.0f);
  if (lane == 0) {
    Wp[(oc * 9 + tap) * 8 + cb * 2]     = (uint)m;
    Wp[(oc * 9 + tap) * 8 + cb * 2 + 1] = (uint)(m >> 32);
  }
}

// ---------------- conv1: branch-free padded LDS + sliding window -----------
// block = 1 wave = 64 oc; grid (16 ocChunk, 28 y, 32 b)

#define LOADCOL1(J, COL) { const uint4* p = ((const uint4*)apad) + (COL) * 2; \
  win[J][0] = p[0];   win[J][1] = p[1]; \
  win[J][2] = p[60];  win[J][3] = p[61]; \
  win[J][4] = p[120]; win[J][5] = p[121]; }

#define TAP1(J, KH, T9) { \
  uint4 a0 = win[J][(KH)*2], a1 = win[J][(KH)*2+1]; \
  const uint* wp = &wr[(T9)*8]; \
  S += __popc(a0.x ^ wp[0]); S += __popc(a0.y ^ wp[1]); \
  S += __popc(a0.z ^ wp[2]); S += __popc(a0.w ^ wp[3]); \
  S += __popc(a1.x ^ wp[4]); S += __popc(a1.y ^ wp[5]); \
  S += __popc(a1.z ^ wp[6]); S += __popc(a1.w ^ wp[7]); }

#define COMP1(XX, J0, J1, J2, THR) { \
  int S = 0; \
  TAP1(J0,0,0) TAP1(J1,0,1) TAP1(J2,0,2) \
  TAP1(J0,1,3) TAP1(J1,1,4) TAP1(J2,1,5) \
  TAP1(J0,2,6) TAP1(J1,2,7) TAP1(J2,2,8) \
  unsigned long long m = __ballot((float)S < (THR)); \
  if (lane == 0) { outp[(XX)*32] = (uint)m; outp[(XX)*32+1] = (uint)(m >> 32); } }

__global__ __launch_bounds__(64) void kConv1(
    const uint* __restrict__ A1p, const uint* __restrict__ W1p,
    const float* __restrict__ bnA1, const float* __restrict__ bnB1,
    uint* __restrict__ A2p) {
  const int lane = threadIdx.x;
  const int chunk = blockIdx.x, y = blockIdx.y, b = blockIdx.z;
  const int oc = chunk * 64 + lane;

  __shared__ uint apad[720];  // [3 rows][30 cols][8 words], zero padded
  { uint4* z = (uint4*)apad;
    for (int i = lane; i < 180; i += 64) z[i] = make_uint4(0u, 0u, 0u, 0u); }
  __syncthreads();
#pragma unroll
  for (int kh = 0; kh < 3; kh++) {
    int ry = y + kh - 1;
    if (ry < 0 || ry >= 28) continue;
    const uint4* src = (const uint4*)(A1p + (b * 784 + ry * 28) * 8);
    uint4* dst = ((uint4*)apad) + kh * 60 + 2;  // col 1
    if (lane < 56) dst[lane] = src[lane];
  }
  __syncthreads();

  uint wr[72];
  const uint4* wsrc = (const uint4*)(W1p + oc * 72);
#pragma unroll
  for (int i = 0; i < 18; i++) {
    uint4 t = wsrc[i];
    wr[4*i] = t.x; wr[4*i+1] = t.y; wr[4*i+2] = t.z; wr[4*i+3] = t.w;
  }
  int pw[9];
#pragma unroll
  for (int t9 = 0; t9 < 9; t9++) {
    int s = 0;
#pragma unroll
    for (int i = 0; i < 8; i++) s += __popc(wr[t9*8 + i]);
    pw[t9] = s;
  }
  const int ytop = (y > 0) ? 1 : 0, ybot = (y < 27) ? 1 : 0;
  const int nrv = 1 + ytop + ybot;
  int pwInvRow = 0;
  if (!ytop) pwInvRow += pw[0] + pw[1] + pw[2];
  if (!ybot) pwInvRow += pw[6] + pw[7] + pw[8];
  int pwV0 = pw[3], pwV2 = pw[5];
  if (ytop) { pwV0 += pw[0]; pwV2 += pw[2]; }
  if (ybot) { pwV0 += pw[6]; pwV2 += pw[8]; }
  const float inv = bnA1[oc], bb = bnB1[oc];
  const float tneg = -bb / inv;  // bn1_scale >= 0 -> inv >= 0
  const float thrM  = ((float)(256 * 3 * nrv + 2 * pwInvRow) - tneg) * 0.5f;
  const float thr0  = ((float)(256 * 2 * nrv + 2 * (pwInvRow + pwV0)) - tneg) * 0.5f;
  const float thr27 = ((float)(256 * 2 * nrv + 2 * (pwInvRow + pwV2)) - tneg) * 0.5f;

  uint* outp = A2p + (b * 784 + y * 28) * 32 + chunk * 2;
  uint4 win[3][6];
  LOADCOL1(0, 0) LOADCOL1(1, 1) LOADCOL1(2, 2)
  COMP1(0, 0, 1, 2, thr0)
  for (int xb = 1; xb <= 25; xb += 3) {
    LOADCOL1(0, xb + 2) COMP1(xb,     1, 2, 0, thrM)
    LOADCOL1(1, xb + 3) COMP1(xb + 1, 2, 0, 1, thrM)
    LOADCOL1(2, xb + 4) COMP1(xb + 2, 0, 1, 2, (xb == 25) ? thr27 : thrM)
  }
}

// Per-(pixel,group) popcount of A2
__global__ __launch_bounds__(256) void kS(const uint* __restrict__ A2p,
                                          uint* __restrict__ S) {
  int idx = blockIdx.x * 256 + threadIdx.x;
  if (idx >= 25088 * 4) return;
  int pix = idx >> 2, g = idx & 3;
  const uint* p = A2p + pix * 32 + g * 8;
  int t = 0;
#pragma unroll
  for (int w = 0; w < 8; w++) t += __popc(p[w]);
  S[idx] = (uint)t;
}

// 3x3 zero-padded box sum of S -> float
__global__ __launch_bounds__(256) void kBS(const uint* __restrict__ S,
                                           float* __restrict__ BSf) {
  int idx = blockIdx.x * 256 + threadIdx.x;
  if (idx >= 25088 * 4) return;
  int pix = idx >> 2, g = idx & 3;
  int b = pix / 784, rem = pix - b * 784;
  int y = rem / 28, x = rem - y * 28;
  int t = 0;
  for (int dy = -1; dy <= 1; dy++) {
    int ry = y + dy;
    if (ry < 0 || ry >= 28) continue;
    for (int dx = -1; dx <= 1; dx++) {
      int rx = x + dx;
      if (rx < 0 || rx >= 28) continue;
      t += (int)S[((b * 784 + ry * 28 + rx) << 2) + g];
    }
  }
  BSf[idx] = (float)t;
}

// ---------------- conv2: wave = group, padded LDS, sliding window ----------
// block 256 = 4 waves; grid (4 cchunk, 28 y, 32 b)

#define LOADCOL2(J, COL) { const uint4* p = ((const uint4*)apad) + (COL) * 8 + g * 2; \
  win[J][0] = p[0];   win[J][1] = p[1]; \
  win[J][2] = p[240]; win[J][3] = p[241]; \
  win[J][4] = p[480]; win[J][5] = p[481]; }

#define TAP2(J, KH, T9) { \
  uint4 a0 = win[J][(KH)*2], a1 = win[J][(KH)*2+1]; \
  const uint* wp = &wr[(T9)*8]; \
  S += __popc(a0.x & wp[0]); S += __popc(a0.y & wp[1]); \
  S += __popc(a0.z & wp[2]); S += __popc(a0.w & wp[3]); \
  S += __popc(a1.x & wp[4]); S += __popc(a1.y & wp[5]); \
  S += __popc(a1.z & wp[6]); S += __popc(a1.w & wp[7]); }

#define COMP2(XX, J0, J1, J2) { \
  int S = 0; \
  TAP2(J0,0,0) TAP2(J1,0,1) TAP2(J2,0,2) \
  TAP2(J0,1,3) TAP2(J1,1,4) TAP2(J2,1,5) \
  TAP2(J0,2,6) TAP2(J1,2,7) TAP2(J2,2,8) \
  float bs = bsrow[(XX)*4 + g]; \
  vrow[XX] = fmaf((float)S, inv2, fmaf(-inv, bs, bb)); }

__global__ __launch_bounds__(256) void kConv2(
    const uint* __restrict__ A2p, const uint* __restrict__ W2p,
    const float* __restrict__ BSf,
    const float* __restrict__ bnA2, const float* __restrict__ bnB2,
    const float* __restrict__ xin, float* __restrict__ out) {
  const int tid = threadIdx.x;
  const int lane = tid & 63, g = tid >> 6;
  const int cchunk = blockIdx.x, y = blockIdx.y, b = blockIdx.z;
  const int oc = g * 256 + cchunk * 64 + lane;

  __shared__ uint apad[2880];       // [3][30][32] zero padded
  __shared__ float bsrow[112];      // [28 x][4 g]
  __shared__ float vals[4][64][28];

  { uint4* z = (uint4*)apad;
    for (int i = tid; i < 720; i += 256) z[i] = make_uint4(0u, 0u, 0u, 0u); }
  if (tid < 112) bsrow[tid] = BSf[(b * 784 + y * 28) * 4 + tid];
  __syncthreads();
#pragma unroll
  for (int kh = 0; kh < 3; kh++) {
    int ry = y + kh - 1;
    if (ry < 0 || ry >= 28) continue;
    const uint4* src = (const uint4*)(A2p + (b * 784 + ry * 28) * 32);
    if (tid < 224) {
      int col = tid >> 3, h = tid & 7;
      ((uint4*)apad)[kh * 240 + (col + 1) * 8 + h] = src[tid];
    }
  }
  __syncthreads();

  uint wr[72];
  const uint4* wsrc = (const uint4*)(W2p + oc * 72);
#pragma unroll
  for (int i = 0; i < 18; i++) {
    uint4 t = wsrc[i];
    wr[4*i] = t.x; wr[4*i+1] = t.y; wr[4*i+2] = t.z; wr[4*i+3] = t.w;
  }
  const float inv = bnA2[oc], bb = bnB2[oc];
  const float inv2 = 2.0f * inv;
  float* vrow = &vals[g][lane][0];

  uint4 win[3][6];
  LOADCOL2(0, 0) LOADCOL2(1, 1) LOADCOL2(2, 2)
  COMP2(0, 0, 1, 2)
  for (int xb = 1; xb <= 25; xb += 3) {
    LOADCOL2(0, xb + 2) COMP2(xb,     1, 2, 0)
    LOADCOL2(1, xb + 3) COMP2(xb + 1, 2, 0, 1)
    LOADCOL2(2, xb + 4) COMP2(xb + 2, 0, 1, 2)
  }
  __syncthreads();

  const int c = tid >> 2, xs = tid & 3;
  const long obase = ((long)(b * 256 + cchunk * 64 + c) * 28 + y) * 28;
#pragma unroll
  for (int k = 0; k < 7; k++) {
    int x = xs + 4 * k;
    float v = vals[0][c][x] + vals[1][c][x] + vals[2][c][x] + vals[3][c][x];
    float o = v + xin[obase + x];
    out[obase + x] = fmaxf(o, 0.0f);
  }
}

extern "C" void kernel_launch(void* const* d_in, const int* in_sizes, int n_in,
                              void* d_out, int out_size, void* d_ws, size_t ws_size,
                              hipStream_t stream) {
  const float* x   = (const float*)d_in[0];
  const float* w1  = (const float*)d_in[1];
  const float* s1  = (const float*)d_in[2];
  const float* b1  = (const float*)d_in[3];
  const float* m1  = (const float*)d_in[4];
  const float* v1  = (const float*)d_in[5];
  const float* w2  = (const float*)d_in[6];
  const float* s2  = (const float*)d_in[7];
  const float* b2  = (const float*)d_in[8];
  const float* m2  = (const float*)d_in[9];
  const float* v2  = (const float*)d_in[10];
  const float* lam = (const float*)d_in[11];
  float* out = (float*)d_out;

  char* ws = (char*)d_ws;
  uint*  A1p  = (uint*)(ws + 0);          //   802816 B
  uint*  W1p  = (uint*)(ws + 802816);     //   294912 B
  uint*  W2p  = (uint*)(ws + 1097728);    //   294912 B
  uint*  A2p  = (uint*)(ws + 1392640);    //  3211264 B
  uint*  Sb   = (uint*)(ws + 4603904);    //   401408 B
  float* BSf  = (float*)(ws + 5005312);   //   401408 B
  float* bnA1 = (float*)(ws + 5406720);
  float* bnB1 = (float*)(ws + 5410816);
  float* bnA2 = (float*)(ws + 5414912);
  float* bnB2 = (float*)(ws + 5419008);

  kPrep<<<4, 256, 0, stream>>>(s1, b1, m1, v1, s2, b2, m2, v2, lam,
                               bnA1, bnB1, bnA2, bnB2);
  kPackX<<<25088, 256, 0, stream>>>(x, A1p);
  kPackW<<<9216, 256, 0, stream>>>(w1, W1p);
  kPackW<<<9216, 256, 0, stream>>>(w2, W2p);
  kConv1<<<dim3(16, 28, 32), 64, 0, stream>>>(A1p, W1p, bnA1, bnB1, A2p);
  kS<<<(25088 * 4 + 255) / 256, 256, 0, stream>>>(A2p, Sb);
  kBS<<<(25088 * 4 + 255) / 256, 256, 0, stream>>>(Sb, BSf);
  kConv2<<<dim3(4, 28, 32), 256, 0, stream>>>(A2p, W2p, BSf, bnA2, bnB2, x, out);
}

// Round 3
// 361.015 us; speedup vs baseline: 1.0877x; 1.0877x over previous
//
#include <hip/hip_runtime.h>
#include <cstdint>

#define BN_EPS 1e-5f

typedef unsigned int uint;

// ---------------------------------------------------------------------------
// x:  (32, 256, 28, 28) f32
// w1: (1024, 256, 3, 3)  conv1: 256 -> 1024 (groups collapse: same input)
// w2: (1024, 256, 3, 3)  conv2: grouped x4
// out: (32, 256, 28, 28) f32
// Packing: 256 ch -> 8 u32 words; bit (c%32) of word (c/32) = (v>=0)
//
// Column decomposition: out(x) = q0(col x-1) + q1(col x) + q2(col x+1),
// q_kw(col) = sum_kh popc(a[kh][col] op w[kh][kw]). Rolling regs a0,a1.
// ---------------------------------------------------------------------------

__global__ __launch_bounds__(256) void kPrep(
    const float* __restrict__ s1, const float* __restrict__ b1,
    const float* __restrict__ m1, const float* __restrict__ v1,
    const float* __restrict__ s2, const float* __restrict__ b2,
    const float* __restrict__ m2, const float* __restrict__ v2,
    const float* __restrict__ lam,
    float* __restrict__ bnA1, float* __restrict__ bnB1,
    float* __restrict__ bnA2, float* __restrict__ bnB2) {
  int t = blockIdx.x * 256 + threadIdx.x;
  if (t >= 1024) return;
  float inv1 = s1[t] / sqrtf(v1[t] + BN_EPS);
  bnA1[t] = inv1;
  bnB1[t] = b1[t] - m1[t] * inv1;
  float inv2 = s2[t] / sqrtf(v2[t] + BN_EPS);
  float l = lam[t >> 8];
  bnA2[t] = inv2 * l;
  bnB2[t] = (b2[t] - m2[t] * inv2) * l;
}

__global__ __launch_bounds__(256) void kPackX(const float* __restrict__ x,
                                              uint* __restrict__ A1p) {
  int wg = blockIdx.x * 4 + (threadIdx.x >> 6);
  int lane = threadIdx.x & 63;
  int pixel = wg >> 2;
  int cb = wg & 3;
  int b = pixel / 784;
  int rem = pixel - b * 784;
  float v = x[(b * 256 + cb * 64 + lane) * 784 + rem];
  unsigned long long m = __ballot(v >= 0.0f);
  if (lane == 0) {
    A1p[pixel * 8 + cb * 2]     = (uint)m;
    A1p[pixel * 8 + cb * 2 + 1] = (uint)(m >> 32);
  }
}

__global__ __launch_bounds__(256) void kPackW(const float* __restrict__ w,
                                              uint* __restrict__ Wp) {
  int wg = blockIdx.x * 4 + (threadIdx.x >> 6);
  int lane = threadIdx.x & 63;
  int oc = wg / 36;
  int r = wg - oc * 36;
  int tap = r >> 2;
  int cb = r & 3;
  float v = w[(oc * 256 + cb * 64 + lane) * 9 + tap];
  unsigned long long m = __ballot(v >= 0.0f);
  if (lane == 0) {
    Wp[(oc * 9 + tap) * 8 + cb * 2]     = (uint)m;
    Wp[(oc * 9 + tap) * 8 + cb * 2 + 1] = (uint)(m >> 32);
  }
}

// ---------------- conv1: padded LDS + column decomposition -----------------
// block = 1 wave = 64 oc; grid (16 ocChunk, 28 y, 32 b)

#define XP8(A0, A1, WP) (__popc((A0).x ^ (WP)[0]) + __popc((A0).y ^ (WP)[1]) + \
                         __popc((A0).z ^ (WP)[2]) + __popc((A0).w ^ (WP)[3]) + \
                         __popc((A1).x ^ (WP)[4]) + __popc((A1).y ^ (WP)[5]) + \
                         __popc((A1).z ^ (WP)[6]) + __popc((A1).w ^ (WP)[7]))

#define COL1(P, D0, D1, D2, EMIT, X, THR) { \
  const uint4* ap = ((const uint4*)apad) + (P) * 2; \
  int q0 = 0, q1 = 0, q2 = 0; \
  { uint4 ra = ap[0],   rb = ap[1]; \
    if (D0) q0 += XP8(ra, rb, wr + 0);  if (D1) q1 += XP8(ra, rb, wr + 8); \
    if (D2) q2 += XP8(ra, rb, wr + 16); } \
  { uint4 ra = ap[60],  rb = ap[61]; \
    if (D0) q0 += XP8(ra, rb, wr + 24); if (D1) q1 += XP8(ra, rb, wr + 32); \
    if (D2) q2 += XP8(ra, rb, wr + 40); } \
  { uint4 ra = ap[120], rb = ap[121]; \
    if (D0) q0 += XP8(ra, rb, wr + 48); if (D1) q1 += XP8(ra, rb, wr + 56); \
    if (D2) q2 += XP8(ra, rb, wr + 64); } \
  if (EMIT) { int Sx = a0 + q2; \
    unsigned long long m = __ballot((float)Sx < (THR)); \
    if (lane == 0) { outp[(X) * 32] = (uint)m; outp[(X) * 32 + 1] = (uint)(m >> 32); } } \
  a0 = a1 + q1; a1 = q0; }

__global__ __launch_bounds__(64) void kConv1(
    const uint* __restrict__ A1p, const uint* __restrict__ W1p,
    const float* __restrict__ bnA1, const float* __restrict__ bnB1,
    uint* __restrict__ A2p) {
  const int lane = threadIdx.x;
  const int chunk = blockIdx.x, y = blockIdx.y, b = blockIdx.z;
  const int oc = chunk * 64 + lane;

  __shared__ uint apad[720];  // [3 rows][30 cols][8 words], zero padded
  { uint4* z = (uint4*)apad;
    for (int i = lane; i < 180; i += 64) z[i] = make_uint4(0u, 0u, 0u, 0u); }
  __syncthreads();
#pragma unroll
  for (int kh = 0; kh < 3; kh++) {
    int ry = y + kh - 1;
    if (ry < 0 || ry >= 28) continue;
    const uint4* src = (const uint4*)(A1p + (b * 784 + ry * 28) * 8);
    uint4* dst = ((uint4*)apad) + kh * 60 + 2;  // col 1
    if (lane < 56) dst[lane] = src[lane];
  }
  __syncthreads();

  uint wr[72];
  const uint4* wsrc = (const uint4*)(W1p + oc * 72);
#pragma unroll
  for (int i = 0; i < 18; i++) {
    uint4 t = wsrc[i];
    wr[4*i] = t.x; wr[4*i+1] = t.y; wr[4*i+2] = t.z; wr[4*i+3] = t.w;
  }
  int pw[9];
#pragma unroll
  for (int t9 = 0; t9 < 9; t9++) {
    int s = 0;
#pragma unroll
    for (int i = 0; i < 8; i++) s += __popc(wr[t9*8 + i]);
    pw[t9] = s;
  }
  const int ytop = (y > 0) ? 1 : 0, ybot = (y < 27) ? 1 : 0;
  const int nrv = 1 + ytop + ybot;
  int pwInvRow = 0;
  if (!ytop) pwInvRow += pw[0] + pw[1] + pw[2];
  if (!ybot) pwInvRow += pw[6] + pw[7] + pw[8];
  int pwV0 = pw[3], pwV2 = pw[5];
  if (ytop) { pwV0 += pw[0]; pwV2 += pw[2]; }
  if (ybot) { pwV0 += pw[6]; pwV2 += pw[8]; }
  const float inv = bnA1[oc], bb = bnB1[oc];
  const float tneg = -bb / inv;  // bn1_scale >= 0 -> inv >= 0
  const float thrM  = ((float)(256 * 3 * nrv + 2 * pwInvRow) - tneg) * 0.5f;
  const float thr0  = ((float)(256 * 2 * nrv + 2 * (pwInvRow + pwV0)) - tneg) * 0.5f;
  const float thr27 = ((float)(256 * 2 * nrv + 2 * (pwInvRow + pwV2)) - tneg) * 0.5f;

  uint* outp = A2p + (b * 784 + y * 28) * 32 + chunk * 2;
  int a0 = 0, a1 = 0;
  COL1(0, 1, 0, 0, 0, 0, 0.0f)
  COL1(1, 1, 1, 0, 0, 0, 0.0f)
  COL1(2, 1, 1, 1, 1, 0, thr0)
#pragma unroll
  for (int p = 3; p <= 27; ++p) { COL1(p, 1, 1, 1, 1, (p - 2), thrM) }
  COL1(28, 0, 1, 1, 1, 26, thrM)
  COL1(29, 0, 0, 1, 1, 27, thr27)
}

// Per-(pixel,group) popcount of A2
__global__ __launch_bounds__(256) void kS(const uint* __restrict__ A2p,
                                          uint* __restrict__ S) {
  int idx = blockIdx.x * 256 + threadIdx.x;
  if (idx >= 25088 * 4) return;
  int pix = idx >> 2, g = idx & 3;
  const uint* p = A2p + pix * 32 + g * 8;
  int t = 0;
#pragma unroll
  for (int w = 0; w < 8; w++) t += __popc(p[w]);
  S[idx] = (uint)t;
}

// 3x3 zero-padded box sum of S -> float
__global__ __launch_bounds__(256) void kBS(const uint* __restrict__ S,
                                           float* __restrict__ BSf) {
  int idx = blockIdx.x * 256 + threadIdx.x;
  if (idx >= 25088 * 4) return;
  int pix = idx >> 2, g = idx & 3;
  int b = pix / 784, rem = pix - b * 784;
  int y = rem / 28, x = rem - y * 28;
  int t = 0;
  for (int dy = -1; dy <= 1; dy++) {
    int ry = y + dy;
    if (ry < 0 || ry >= 28) continue;
    for (int dx = -1; dx <= 1; dx++) {
      int rx = x + dx;
      if (rx < 0 || rx >= 28) continue;
      t += (int)S[((b * 784 + ry * 28 + rx) << 2) + g];
    }
  }
  BSf[idx] = (float)t;
}

// ---------------- conv2: round-1 mapping + padded LDS + columns ------------
// block 256 = 4 waves; wave xq owns x-strip [xq*7, xq*7+6], lane = c;
// grid (4 cchunk, 28 y, 32 b). Direct register epilogue (no LDS vals).

#define AP8(A0, A1, WP) (__popc((A0).x & (WP)[0]) + __popc((A0).y & (WP)[1]) + \
                         __popc((A0).z & (WP)[2]) + __popc((A0).w & (WP)[3]) + \
                         __popc((A1).x & (WP)[4]) + __popc((A1).y & (WP)[5]) + \
                         __popc((A1).z & (WP)[6]) + __popc((A1).w & (WP)[7]))

#define COL2(P, D0, D1, D2, EMIT, XI) { \
  const uint4* ap = ((const uint4*)apad) + (P) * 8 + g * 2; \
  int q0 = 0, q1 = 0, q2 = 0; \
  { uint4 ra = ap[0],   rb = ap[1]; \
    if (D0) q0 += AP8(ra, rb, wr + 0);  if (D1) q1 += AP8(ra, rb, wr + 8); \
    if (D2) q2 += AP8(ra, rb, wr + 16); } \
  { uint4 ra = ap[240], rb = ap[241]; \
    if (D0) q0 += AP8(ra, rb, wr + 24); if (D1) q1 += AP8(ra, rb, wr + 32); \
    if (D2) q2 += AP8(ra, rb, wr + 40); } \
  { uint4 ra = ap[480], rb = ap[481]; \
    if (D0) q0 += AP8(ra, rb, wr + 48); if (D1) q1 += AP8(ra, rb, wr + 56); \
    if (D2) q2 += AP8(ra, rb, wr + 64); } \
  if (EMIT) { int Sx = a0 + q2; \
    float bs = bsrow[(s + (XI)) * 4 + g]; \
    val[XI] += fmaf((float)Sx, inv2, fmaf(-inv, bs, bb)); } \
  a0 = a1 + q1; a1 = q0; }

__global__ __launch_bounds__(256) void kConv2(
    const uint* __restrict__ A2p, const uint* __restrict__ W2p,
    const float* __restrict__ BSf,
    const float* __restrict__ bnA2, const float* __restrict__ bnB2,
    const float* __restrict__ xin, float* __restrict__ out) {
  const int tid = threadIdx.x;
  const int lane = tid & 63, xq = tid >> 6;
  const int cchunk = blockIdx.x, y = blockIdx.y, b = blockIdx.z;
  const int s = xq * 7;

  __shared__ uint apad[2880];   // [3 rows][30 cols][32 words], zero padded
  __shared__ float bsrow[112];  // [28 x][4 g]

  { uint4* z = (uint4*)apad;
    for (int i = tid; i < 720; i += 256) z[i] = make_uint4(0u, 0u, 0u, 0u); }
  if (tid < 112) bsrow[tid] = BSf[(b * 784 + y * 28) * 4 + tid];
  __syncthreads();
#pragma unroll
  for (int kh = 0; kh < 3; kh++) {
    int ry = y + kh - 1;
    if (ry < 0 || ry >= 28) continue;
    const uint4* src = (const uint4*)(A2p + (b * 784 + ry * 28) * 32);
    if (tid < 224) {
      int col = tid >> 3, h = tid & 7;
      ((uint4*)apad)[kh * 240 + (col + 1) * 8 + h] = src[tid];
    }
  }
  __syncthreads();

  float val[7];
#pragma unroll
  for (int i = 0; i < 7; i++) val[i] = 0.0f;

  for (int g = 0; g < 4; g++) {
    const int oc = g * 256 + cchunk * 64 + lane;
    uint wr[72];
    const uint4* wsrc = (const uint4*)(W2p + oc * 72);
#pragma unroll
    for (int i = 0; i < 18; i++) {
      uint4 t = wsrc[i];
      wr[4*i] = t.x; wr[4*i+1] = t.y; wr[4*i+2] = t.z; wr[4*i+3] = t.w;
    }
    const float inv = bnA2[oc], bb = bnB2[oc];
    const float inv2 = 2.0f * inv;
    int a0 = 0, a1 = 0;
    COL2(s + 0, 1, 0, 0, 0, 0)
    COL2(s + 1, 1, 1, 0, 0, 0)
    COL2(s + 2, 1, 1, 1, 1, 0)
    COL2(s + 3, 1, 1, 1, 1, 1)
    COL2(s + 4, 1, 1, 1, 1, 2)
    COL2(s + 5, 1, 1, 1, 1, 3)
    COL2(s + 6, 1, 1, 1, 1, 4)
    COL2(s + 7, 0, 1, 1, 1, 5)
    COL2(s + 8, 0, 0, 1, 1, 6)
  }

  const int c = cchunk * 64 + lane;
  const int obase = ((b * 256 + c) * 28 + y) * 28;
#pragma unroll
  for (int xi = 0; xi < 7; xi++) {
    int x = s + xi;
    float o = val[xi] + xin[obase + x];
    out[obase + x] = fmaxf(o, 0.0f);
  }
}

extern "C" void kernel_launch(void* const* d_in, const int* in_sizes, int n_in,
                              void* d_out, int out_size, void* d_ws, size_t ws_size,
                              hipStream_t stream) {
  const float* x   = (const float*)d_in[0];
  const float* w1  = (const float*)d_in[1];
  const float* s1  = (const float*)d_in[2];
  const float* b1  = (const float*)d_in[3];
  const float* m1  = (const float*)d_in[4];
  const float* v1  = (const float*)d_in[5];
  const float* w2  = (const float*)d_in[6];
  const float* s2  = (const float*)d_in[7];
  const float* b2  = (const float*)d_in[8];
  const float* m2  = (const float*)d_in[9];
  const float* v2  = (const float*)d_in[10];
  const float* lam = (const float*)d_in[11];
  float* out = (float*)d_out;

  char* ws = (char*)d_ws;
  uint*  A1p  = (uint*)(ws + 0);          //   802816 B
  uint*  W1p  = (uint*)(ws + 802816);     //   294912 B
  uint*  W2p  = (uint*)(ws + 1097728);    //   294912 B
  uint*  A2p  = (uint*)(ws + 1392640);    //  3211264 B
  uint*  Sb   = (uint*)(ws + 4603904);    //   401408 B
  float* BSf  = (float*)(ws + 5005312);   //   401408 B
  float* bnA1 = (float*)(ws + 5406720);
  float* bnB1 = (float*)(ws + 5410816);
  float* bnA2 = (float*)(ws + 5414912);
  float* bnB2 = (float*)(ws + 5419008);

  kPrep<<<4, 256, 0, stream>>>(s1, b1, m1, v1, s2, b2, m2, v2, lam,
                               bnA1, bnB1, bnA2, bnB2);
  kPackX<<<25088, 256, 0, stream>>>(x, A1p);
  kPackW<<<9216, 256, 0, stream>>>(w1, W1p);
  kPackW<<<9216, 256, 0, stream>>>(w2, W2p);
  kConv1<<<dim3(16, 28, 32), 64, 0, stream>>>(A1p, W1p, bnA1, bnB1, A2p);
  kS<<<(25088 * 4 + 255) / 256, 256, 0, stream>>>(A2p, Sb);
  kBS<<<(25088 * 4 + 255) / 256, 256, 0, stream>>>(Sb, BSf);
  kConv2<<<dim3(4, 28, 32), 256, 0, stream>>>(A2p, W2p, BSf, bnA2, bnB2, x, out);
}

// Round 4
// 346.392 us; speedup vs baseline: 1.1336x; 1.0422x over previous
//
#include <hip/hip_runtime.h>
#include <cstdint>

#define BN_EPS 1e-5f

typedef unsigned int uint;

// ---------------------------------------------------------------------------
// x:  (32, 256, 28, 28) f32
// w1: (1024, 256, 3, 3)  conv1: 256 -> 1024 (groups collapse: same input)
// w2: (1024, 256, 3, 3)  conv2: grouped x4
// out: (32, 256, 28, 28) f32
// Packing: 256 ch -> 8 u32 words; bit (c%32) of word (c/32) = (v>=0)
//
// Column decomposition: out(x) = q0(col x-1) + q1(col x) + q2(col x+1),
// q_kw(col) = sum_kh popc(a[kh][col] op w[kh][kw]). Rolling regs a0,a1.
// kConv1: 4-wave blocks share LDS tile; main loop ROLLED (3 cols/iter) to
// stay inside the 32KB I-cache (r3's full unroll regressed 135->198us).
// ---------------------------------------------------------------------------

__global__ __launch_bounds__(256) void kPrep(
    const float* __restrict__ s1, const float* __restrict__ b1,
    const float* __restrict__ m1, const float* __restrict__ v1,
    const float* __restrict__ s2, const float* __restrict__ b2,
    const float* __restrict__ m2, const float* __restrict__ v2,
    const float* __restrict__ lam,
    float* __restrict__ bnA1, float* __restrict__ bnB1,
    float* __restrict__ bnA2, float* __restrict__ bnB2) {
  int t = blockIdx.x * 256 + threadIdx.x;
  if (t >= 1024) return;
  float inv1 = s1[t] / sqrtf(v1[t] + BN_EPS);
  bnA1[t] = inv1;
  bnB1[t] = b1[t] - m1[t] * inv1;
  float inv2 = s2[t] / sqrtf(v2[t] + BN_EPS);
  float l = lam[t >> 8];
  bnA2[t] = inv2 * l;
  bnB2[t] = (b2[t] - m2[t] * inv2) * l;
}

// Each lane reads one full 64B line (16 consecutive px of its channel),
// then 16 ballots pack channel bits. Every line of x fetched exactly once.
__global__ __launch_bounds__(256) void kPackX(const float* __restrict__ x,
                                              uint* __restrict__ A1p) {
  const int tid = threadIdx.x;
  const int lane = tid & 63, cb = tid >> 6;
  const int grp = blockIdx.x;  // 0..1567 = 32 b * 49 groups of 16 px
  const int b = grp / 49, r16 = (grp % 49) * 16;
  const float4* src = (const float4*)(x + ((b * 256 + cb * 64 + lane) * 784 + r16));
  float4 f0 = src[0], f1 = src[1], f2 = src[2], f3 = src[3];
  uint* outp = A1p + (b * 784 + r16) * 8 + cb * 2;
#define PB(V, PX) { unsigned long long m = __ballot((V) >= 0.0f); \
    if (lane == 0) { outp[(PX)*8] = (uint)m; outp[(PX)*8+1] = (uint)(m>>32); } }
  PB(f0.x, 0)  PB(f0.y, 1)  PB(f0.z, 2)  PB(f0.w, 3)
  PB(f1.x, 4)  PB(f1.y, 5)  PB(f1.z, 6)  PB(f1.w, 7)
  PB(f2.x, 8)  PB(f2.y, 9)  PB(f2.z, 10) PB(f2.w, 11)
  PB(f3.x, 12) PB(f3.y, 13) PB(f3.z, 14) PB(f3.w, 15)
#undef PB
}

__global__ __launch_bounds__(256) void kPackW(const float* __restrict__ w,
                                              uint* __restrict__ Wp) {
  int wg = blockIdx.x * 4 + (threadIdx.x >> 6);
  int lane = threadIdx.x & 63;
  int oc = wg / 36;
  int r = wg - oc * 36;
  int tap = r >> 2;
  int cb = r & 3;
  float v = w[(oc * 256 + cb * 64 + lane) * 9 + tap];
  unsigned long long m = __ballot(v >= 0.0f);
  if (lane == 0) {
    Wp[(oc * 9 + tap) * 8 + cb * 2]     = (uint)m;
    Wp[(oc * 9 + tap) * 8 + cb * 2 + 1] = (uint)(m >> 32);
  }
}

// ---------------- conv1: padded LDS + column decomposition -----------------
// block = 256 (4 waves, wave = oc chunk); grid (4 quad, 28 y, 32 b)

#define XP8(A0, A1, WP) (__popc((A0).x ^ (WP)[0]) + __popc((A0).y ^ (WP)[1]) + \
                         __popc((A0).z ^ (WP)[2]) + __popc((A0).w ^ (WP)[3]) + \
                         __popc((A1).x ^ (WP)[4]) + __popc((A1).y ^ (WP)[5]) + \
                         __popc((A1).z ^ (WP)[6]) + __popc((A1).w ^ (WP)[7]))

#define COL1(P, D0, D1, D2, EMIT, X, THR) { \
  const uint4* ap = ((const uint4*)apad) + (P) * 2; \
  int q0 = 0, q1 = 0, q2 = 0; \
  { uint4 ra = ap[0],   rb = ap[1]; \
    if (D0) q0 += XP8(ra, rb, wr + 0);  if (D1) q1 += XP8(ra, rb, wr + 8); \
    if (D2) q2 += XP8(ra, rb, wr + 16); } \
  { uint4 ra = ap[60],  rb = ap[61]; \
    if (D0) q0 += XP8(ra, rb, wr + 24); if (D1) q1 += XP8(ra, rb, wr + 32); \
    if (D2) q2 += XP8(ra, rb, wr + 40); } \
  { uint4 ra = ap[120], rb = ap[121]; \
    if (D0) q0 += XP8(ra, rb, wr + 48); if (D1) q1 += XP8(ra, rb, wr + 56); \
    if (D2) q2 += XP8(ra, rb, wr + 64); } \
  if (EMIT) { int Sx = a0 + q2; \
    unsigned long long m = __ballot((float)Sx < (THR)); \
    if (lane == 0) { outp[(X) * 32] = (uint)m; outp[(X) * 32 + 1] = (uint)(m >> 32); } } \
  a0 = a1 + q1; a1 = q0; }

__global__ __launch_bounds__(256) void kConv1(
    const uint* __restrict__ A1p, const uint* __restrict__ W1p,
    const float* __restrict__ bnA1, const float* __restrict__ bnB1,
    uint* __restrict__ A2p) {
  const int tid = threadIdx.x;
  const int lane = tid & 63;
  const int quad = blockIdx.x, y = blockIdx.y, b = blockIdx.z;
  const int chunk = quad * 4 + (tid >> 6);
  const int oc = chunk * 64 + lane;

  __shared__ uint apad[720];  // [3 rows][30 cols][8 words], zero padded
  { uint4* z = (uint4*)apad;
    if (tid < 180) z[tid] = make_uint4(0u, 0u, 0u, 0u); }
  __syncthreads();
  if (tid < 168) {  // 3 rows x 56 uint4
    int kh = tid / 56, idx = tid - kh * 56;
    int ry = y + kh - 1;
    if (ry >= 0 && ry < 28) {
      ((uint4*)apad)[kh * 60 + 2 + idx] =
          ((const uint4*)(A1p + (b * 784 + ry * 28) * 8))[idx];
    }
  }
  __syncthreads();

  uint wr[72];
  const uint4* wsrc = (const uint4*)(W1p + oc * 72);
#pragma unroll
  for (int i = 0; i < 18; i++) {
    uint4 t = wsrc[i];
    wr[4*i] = t.x; wr[4*i+1] = t.y; wr[4*i+2] = t.z; wr[4*i+3] = t.w;
  }
  int pw[9];
#pragma unroll
  for (int t9 = 0; t9 < 9; t9++) {
    int s = 0;
#pragma unroll
    for (int i = 0; i < 8; i++) s += __popc(wr[t9*8 + i]);
    pw[t9] = s;
  }
  const int ytop = (y > 0) ? 1 : 0, ybot = (y < 27) ? 1 : 0;
  const int nrv = 1 + ytop + ybot;
  int pwInvRow = 0;
  if (!ytop) pwInvRow += pw[0] + pw[1] + pw[2];
  if (!ybot) pwInvRow += pw[6] + pw[7] + pw[8];
  int pwV0 = pw[3], pwV2 = pw[5];
  if (ytop) { pwV0 += pw[0]; pwV2 += pw[2]; }
  if (ybot) { pwV0 += pw[6]; pwV2 += pw[8]; }
  const float inv = bnA1[oc], bb = bnB1[oc];
  const float tneg = -bb / inv;  // bn1_scale >= 0 -> inv >= 0
  const float thrM  = ((float)(256 * 3 * nrv + 2 * pwInvRow) - tneg) * 0.5f;
  const float thr0  = ((float)(256 * 2 * nrv + 2 * (pwInvRow + pwV0)) - tneg) * 0.5f;
  const float thr27 = ((float)(256 * 2 * nrv + 2 * (pwInvRow + pwV2)) - tneg) * 0.5f;

  uint* outp = A2p + (b * 784 + y * 28) * 32 + chunk * 2;
  int a0 = 0, a1 = 0;
  COL1(0, 1, 0, 0, 0, 0, 0.0f)
  COL1(1, 1, 1, 0, 0, 0, 0.0f)
  COL1(2, 1, 1, 1, 1, 0, thr0)
  for (int p = 3; p <= 24; p += 3) {  // rolled: cols 3..26, emits x=1..24
    COL1(p,     1, 1, 1, 1, (p - 2), thrM)
    COL1(p + 1, 1, 1, 1, 1, (p - 1), thrM)
    COL1(p + 2, 1, 1, 1, 1, (p),     thrM)
  }
  COL1(27, 1, 1, 1, 1, 25, thrM)
  COL1(28, 0, 1, 1, 1, 26, thrM)
  COL1(29, 0, 0, 1, 1, 27, thr27)
}

// Per-(pixel,group) popcount of A2
__global__ __launch_bounds__(256) void kS(const uint* __restrict__ A2p,
                                          uint* __restrict__ S) {
  int idx = blockIdx.x * 256 + threadIdx.x;
  if (idx >= 25088 * 4) return;
  int pix = idx >> 2, g = idx & 3;
  const uint* p = A2p + pix * 32 + g * 8;
  int t = 0;
#pragma unroll
  for (int w = 0; w < 8; w++) t += __popc(p[w]);
  S[idx] = (uint)t;
}

// 3x3 zero-padded box sum of S -> float
__global__ __launch_bounds__(256) void kBS(const uint* __restrict__ S,
                                           float* __restrict__ BSf) {
  int idx = blockIdx.x * 256 + threadIdx.x;
  if (idx >= 25088 * 4) return;
  int pix = idx >> 2, g = idx & 3;
  int b = pix / 784, rem = pix - b * 784;
  int y = rem / 28, x = rem - y * 28;
  int t = 0;
  for (int dy = -1; dy <= 1; dy++) {
    int ry = y + dy;
    if (ry < 0 || ry >= 28) continue;
    for (int dx = -1; dx <= 1; dx++) {
      int rx = x + dx;
      if (rx < 0 || rx >= 28) continue;
      t += (int)S[((b * 784 + ry * 28 + rx) << 2) + g];
    }
  }
  BSf[idx] = (float)t;
}

// ---------------- conv2: wave = x-strip, padded LDS, columns ---------------
// block 256 = 4 waves; wave xq owns x-strip [xq*7, xq*7+6], lane = c;
// grid (4 cchunk, 28 y, 32 b). Direct register epilogue.

#define AP8(A0, A1, WP) (__popc((A0).x & (WP)[0]) + __popc((A0).y & (WP)[1]) + \
                         __popc((A0).z & (WP)[2]) + __popc((A0).w & (WP)[3]) + \
                         __popc((A1).x & (WP)[4]) + __popc((A1).y & (WP)[5]) + \
                         __popc((A1).z & (WP)[6]) + __popc((A1).w & (WP)[7]))

#define COL2(P, D0, D1, D2, EMIT, XI) { \
  const uint4* ap = ((const uint4*)apad) + (P) * 8 + g * 2; \
  int q0 = 0, q1 = 0, q2 = 0; \
  { uint4 ra = ap[0],   rb = ap[1]; \
    if (D0) q0 += AP8(ra, rb, wr + 0);  if (D1) q1 += AP8(ra, rb, wr + 8); \
    if (D2) q2 += AP8(ra, rb, wr + 16); } \
  { uint4 ra = ap[240], rb = ap[241]; \
    if (D0) q0 += AP8(ra, rb, wr + 24); if (D1) q1 += AP8(ra, rb, wr + 32); \
    if (D2) q2 += AP8(ra, rb, wr + 40); } \
  { uint4 ra = ap[480], rb = ap[481]; \
    if (D0) q0 += AP8(ra, rb, wr + 48); if (D1) q1 += AP8(ra, rb, wr + 56); \
    if (D2) q2 += AP8(ra, rb, wr + 64); } \
  if (EMIT) { int Sx = a0 + q2; \
    float bs = bsrow[(s + (XI)) * 4 + g]; \
    val[XI] += fmaf((float)Sx, inv2, fmaf(-inv, bs, bb)); } \
  a0 = a1 + q1; a1 = q0; }

__global__ __launch_bounds__(256) void kConv2(
    const uint* __restrict__ A2p, const uint* __restrict__ W2p,
    const float* __restrict__ BSf,
    const float* __restrict__ bnA2, const float* __restrict__ bnB2,
    const float* __restrict__ xin, float* __restrict__ out) {
  const int tid = threadIdx.x;
  const int lane = tid & 63, xq = tid >> 6;
  const int cchunk = blockIdx.x, y = blockIdx.y, b = blockIdx.z;
  const int s = xq * 7;

  __shared__ uint apad[2880];   // [3 rows][30 cols][32 words], zero padded
  __shared__ float bsrow[112];  // [28 x][4 g]

  { uint4* z = (uint4*)apad;
    for (int i = tid; i < 720; i += 256) z[i] = make_uint4(0u, 0u, 0u, 0u); }
  if (tid < 112) bsrow[tid] = BSf[(b * 784 + y * 28) * 4 + tid];
  __syncthreads();
#pragma unroll
  for (int kh = 0; kh < 3; kh++) {
    int ry = y + kh - 1;
    if (ry < 0 || ry >= 28) continue;
    const uint4* src = (const uint4*)(A2p + (b * 784 + ry * 28) * 32);
    if (tid < 224) {
      int col = tid >> 3, h = tid & 7;
      ((uint4*)apad)[kh * 240 + (col + 1) * 8 + h] = src[tid];
    }
  }
  __syncthreads();

  float val[7];
#pragma unroll
  for (int i = 0; i < 7; i++) val[i] = 0.0f;

  for (int g = 0; g < 4; g++) {
    const int oc = g * 256 + cchunk * 64 + lane;
    uint wr[72];
    const uint4* wsrc = (const uint4*)(W2p + oc * 72);
#pragma unroll
    for (int i = 0; i < 18; i++) {
      uint4 t = wsrc[i];
      wr[4*i] = t.x; wr[4*i+1] = t.y; wr[4*i+2] = t.z; wr[4*i+3] = t.w;
    }
    const float inv = bnA2[oc], bb = bnB2[oc];
    const float inv2 = 2.0f * inv;
    int a0 = 0, a1 = 0;
    COL2(s + 0, 1, 0, 0, 0, 0)
    COL2(s + 1, 1, 1, 0, 0, 0)
    COL2(s + 2, 1, 1, 1, 1, 0)
    COL2(s + 3, 1, 1, 1, 1, 1)
    COL2(s + 4, 1, 1, 1, 1, 2)
    COL2(s + 5, 1, 1, 1, 1, 3)
    COL2(s + 6, 1, 1, 1, 1, 4)
    COL2(s + 7, 0, 1, 1, 1, 5)
    COL2(s + 8, 0, 0, 1, 1, 6)
  }

  const int c = cchunk * 64 + lane;
  const int obase = ((b * 256 + c) * 28 + y) * 28;
#pragma unroll
  for (int xi = 0; xi < 7; xi++) {
    int x = s + xi;
    float o = val[xi] + xin[obase + x];
    out[obase + x] = fmaxf(o, 0.0f);
  }
}

extern "C" void kernel_launch(void* const* d_in, const int* in_sizes, int n_in,
                              void* d_out, int out_size, void* d_ws, size_t ws_size,
                              hipStream_t stream) {
  const float* x   = (const float*)d_in[0];
  const float* w1  = (const float*)d_in[1];
  const float* s1  = (const float*)d_in[2];
  const float* b1  = (const float*)d_in[3];
  const float* m1  = (const float*)d_in[4];
  const float* v1  = (const float*)d_in[5];
  const float* w2  = (const float*)d_in[6];
  const float* s2  = (const float*)d_in[7];
  const float* b2  = (const float*)d_in[8];
  const float* m2  = (const float*)d_in[9];
  const float* v2  = (const float*)d_in[10];
  const float* lam = (const float*)d_in[11];
  float* out = (float*)d_out;

  char* ws = (char*)d_ws;
  uint*  A1p  = (uint*)(ws + 0);          //   802816 B
  uint*  W1p  = (uint*)(ws + 802816);     //   294912 B
  uint*  W2p  = (uint*)(ws + 1097728);    //   294912 B
  uint*  A2p  = (uint*)(ws + 1392640);    //  3211264 B
  uint*  Sb   = (uint*)(ws + 4603904);    //   401408 B
  float* BSf  = (float*)(ws + 5005312);   //   401408 B
  float* bnA1 = (float*)(ws + 5406720);
  float* bnB1 = (float*)(ws + 5410816);
  float* bnA2 = (float*)(ws + 5414912);
  float* bnB2 = (float*)(ws + 5419008);

  kPrep<<<4, 256, 0, stream>>>(s1, b1, m1, v1, s2, b2, m2, v2, lam,
                               bnA1, bnB1, bnA2, bnB2);
  kPackX<<<1568, 256, 0, stream>>>(x, A1p);
  kPackW<<<9216, 256, 0, stream>>>(w1, W1p);
  kPackW<<<9216, 256, 0, stream>>>(w2, W2p);
  kConv1<<<dim3(4, 28, 32), 256, 0, stream>>>(A1p, W1p, bnA1, bnB1, A2p);
  kS<<<(25088 * 4 + 255) / 256, 256, 0, stream>>>(A2p, Sb);
  kBS<<<(25088 * 4 + 255) / 256, 256, 0, stream>>>(Sb, BSf);
  kConv2<<<dim3(4, 28, 32), 256, 0, stream>>>(A2p, W2p, BSf, bnA2, bnB2, x, out);
}